// Round 5
// baseline (314.527 us; speedup 1.0000x reference)
//
#include <hip/hip_runtime.h>
#include <hip/hip_fp16.h>

typedef _Float16 f16;
typedef f16 f16x8 __attribute__((ext_vector_type(8)));
typedef f16 f16x4 __attribute__((ext_vector_type(4)));
typedef float f32x4 __attribute__((ext_vector_type(4)));

constexpr int Bb = 8, Cc = 1024, Tt = 2048, Ci = 512;
constexpr float BN_EPS = 1e-5f;

__device__ __forceinline__ void gload16(const f16* g, f16* l) {
  __builtin_amdgcn_global_load_lds(
      (const __attribute__((address_space(1))) void*)g,
      (__attribute__((address_space(3))) void*)l, 16, 0, 0);
}

// ---------------- fp32 -> fp16 convert (weights) ----------------
__global__ __launch_bounds__(256)
void cvt_kernel(const float* __restrict__ src, f16* __restrict__ dst, int n4) {
  int i = blockIdx.x * blockDim.x + threadIdx.x;
  if (i < n4) {
    float4 v = *((const float4*)src + i);
    f16x4 h;
    h[0] = (f16)v.x; h[1] = (f16)v.y; h[2] = (f16)v.z; h[3] = (f16)v.w;
    *((f16x4*)dst + i) = h;
  }
}

// ---------------- transpose-convert: x[b][c][t] f32 -> xT[b][t][c] f16 ----
__global__ __launch_bounds__(256)
void cvtT_kernel(const float* __restrict__ x, f16* __restrict__ xT) {
  __shared__ float tile[64][68];
  const int b = blockIdx.z, c0 = blockIdx.y * 64, t0 = blockIdx.x * 64;
  const int tid = threadIdx.x;
  const float* xp = x + ((long)b * Cc + c0) * Tt + t0;
  {
    int r = tid >> 4, c4 = (tid & 15) * 4;
    #pragma unroll
    for (int it = 0; it < 4; it++) {
      float4 v = *(const float4*)(xp + (long)(r + it * 16) * Tt + c4);
      *(float4*)&tile[r + it * 16][c4] = v;
    }
  }
  __syncthreads();
  f16* op = xT + ((long)b * Tt + t0) * Cc + c0;
  {
    int c8 = (tid & 7) * 8;
    #pragma unroll
    for (int it = 0; it < 2; it++) {
      int t = (tid >> 3) + it * 32;
      f16x8 o;
      #pragma unroll
      for (int jj = 0; jj < 8; jj++) o[jj] = (f16)tile[c8 + jj][t];
      *(f16x8*)(op + (long)t * Cc + c8) = o;
    }
  }
}

// ============ 8-wave 4-phase 256x256 GEMM: C[m][n] = sum_k A[m][k]*B[n][k] =
// BM=BN=256, BK=64, 8 waves as 2M x 4N (wave tile 128x64).
// LDS: double-buffered, K-major 16B chunks: chunk(khi,row) at (khi*256+row)*16B
// (conflict-free ds_read_b128 by construction). Staging per phase = one K-half
// (2 x global_load_lds). Counted vmcnt(4) at phases 2 and 4.
// BIAS_MODE: 0 none, 1 per-m, 2 per-n (split at 512: bias / bias2).
#define SYNC_LDS() \
  __builtin_amdgcn_s_barrier(); \
  asm volatile("s_waitcnt lgkmcnt(0)" ::: "memory"); \
  __builtin_amdgcn_sched_barrier(0);

#define MFMA_CLUSTER(AH) \
  __builtin_amdgcn_s_setprio(1); \
  _Pragma("unroll") \
  for (int mi = 0; mi < 4; mi++) { \
    _Pragma("unroll") \
    for (int nj = 0; nj < 4; nj++) \
      acc[(AH)*4 + mi][nj] = __builtin_amdgcn_mfma_f32_16x16x32_f16( \
          af[mi], bf[nj], acc[(AH)*4 + mi][nj], 0, 0, 0); \
  } \
  __builtin_amdgcn_s_setprio(0);

template<int BIAS_MODE>
__global__ __launch_bounds__(512, 2)
void gemm256(const f16* __restrict__ A, const f16* __restrict__ B,
             f16* __restrict__ C, const float* __restrict__ bias,
             const float* __restrict__ bias2,
             int K, int lda, int ldb, int ldc, long sA, long sB, long sC)
{
  extern __shared__ f16 lds[];                 // 2 x (16384 A + 16384 B) halves
  const int tid = threadIdx.x, lane = tid & 63, wv = tid >> 6;
  const int bm0 = blockIdx.y * 256, bn0 = blockIdx.x * 256;
  const int wm = wv >> 2, wn = wv & 3;         // 2M x 4N
  const f16* Ab = A + blockIdx.z * sA + (long)bm0 * lda;
  const f16* Bt = B + blockIdx.z * sB + (long)bn0 * ldb;
  C += blockIdx.z * sC;
  const int r16 = lane & 15, khi4 = lane >> 4;
  const int trow = tid & 255, tkq = tid >> 8;

  // stage chunk-call q (khi = 2q+tkq, all 256 rows), linear LDS dest
  auto stA = [&](int nsel, int q, int k0) {
    gload16(Ab + (long)trow * lda + k0 + (2 * q + tkq) * 8,
            lds + nsel * 32768 + (q * 512 + wv * 64) * 8);
  };
  auto stB = [&](int nsel, int q, int k0) {
    gload16(Bt + (long)trow * ldb + k0 + (2 * q + tkq) * 8,
            lds + nsel * 32768 + 16384 + (q * 512 + wv * 64) * 8);
  };

  f32x4 acc[8][4] = {};
  const int nt = K >> 6;
  const int aoff = (khi4 * 256 + wm * 128 + r16) * 8;   // halves, ks0, row-half 0
  const int boff = (khi4 * 256 + wn * 64 + r16) * 8;

  // prologue: tile 0 in order A-K0, B-K0, A-K1, B-K1 (8 loads)
  stA(0, 0, 0); stA(0, 1, 0);
  stB(0, 0, 0); stB(0, 1, 0);
  stA(0, 2, 0); stA(0, 3, 0);
  stB(0, 2, 0); stB(0, 3, 0);
  asm volatile("s_waitcnt vmcnt(4)" ::: "memory");      // A-K0,B-K0 landed
  __builtin_amdgcn_s_barrier();
  __builtin_amdgcn_sched_barrier(0);

  for (int t = 0; t < nt; t++) {
    const int bsel = t & 1, nsel = bsel ^ 1, kn = (t + 1) << 6;
    const bool st = (t + 1) < nt;
    const f16* lA = lds + bsel * 32768;
    const f16* lB = lA + 16384;
    f16x8 af[4], bf[4];

    // ---- phase 1: stage A-K0(t+1); read A[h0,ks0] + B[ks0]; MFMA h0/ks0
    if (st) { stA(nsel, 0, kn); stA(nsel, 1, kn); }
    #pragma unroll
    for (int mi = 0; mi < 4; mi++) af[mi] = *(const f16x8*)(lA + aoff + mi * 128);
    #pragma unroll
    for (int nj = 0; nj < 4; nj++) bf[nj] = *(const f16x8*)(lB + boff + nj * 128);
    SYNC_LDS();
    MFMA_CLUSTER(0);
    __builtin_amdgcn_s_barrier();

    // ---- phase 2: stage B-K0(t+1); read A[h1,ks0]; MFMA h1/ks0; vmcnt(4)
    if (st) { stB(nsel, 0, kn); stB(nsel, 1, kn); }
    #pragma unroll
    for (int mi = 0; mi < 4; mi++) af[mi] = *(const f16x8*)(lA + aoff + 512 + mi * 128);
    SYNC_LDS();
    MFMA_CLUSTER(1);
    if (st) asm volatile("s_waitcnt vmcnt(4)" ::: "memory");  // A-K1,B-K1(t) landed
    else    asm volatile("s_waitcnt vmcnt(0)" ::: "memory");
    __builtin_amdgcn_s_barrier();
    __builtin_amdgcn_sched_barrier(0);

    // ---- phase 3: stage A-K1(t+1); read A[h0,ks1] + B[ks1]; MFMA h0/ks1
    if (st) { stA(nsel, 2, kn); stA(nsel, 3, kn); }
    #pragma unroll
    for (int mi = 0; mi < 4; mi++) af[mi] = *(const f16x8*)(lA + aoff + 8192 + mi * 128);
    #pragma unroll
    for (int nj = 0; nj < 4; nj++) bf[nj] = *(const f16x8*)(lB + boff + 8192 + nj * 128);
    SYNC_LDS();
    MFMA_CLUSTER(0);
    __builtin_amdgcn_s_barrier();

    // ---- phase 4: stage B-K1(t+1); read A[h1,ks1]; MFMA h1/ks1; vmcnt(4)
    if (st) { stB(nsel, 2, kn); stB(nsel, 3, kn); }
    #pragma unroll
    for (int mi = 0; mi < 4; mi++) af[mi] = *(const f16x8*)(lA + aoff + 8704 + mi * 128);
    SYNC_LDS();
    MFMA_CLUSTER(1);
    if (st) asm volatile("s_waitcnt vmcnt(4)" ::: "memory");  // A-K0,B-K0(t+1) landed
    __builtin_amdgcn_s_barrier();
    __builtin_amdgcn_sched_barrier(0);
  }

  // epilogue: acc[i][nj], rows (i>>2)*64 + (i&3)*16
  const int rg = khi4 * 4;
  #pragma unroll
  for (int i = 0; i < 8; i++) {
    const int row = bm0 + wm * 128 + (i >> 2) * 64 + (i & 3) * 16 + rg;
    #pragma unroll
    for (int nj = 0; nj < 4; nj++) {
      const int col = bn0 + wn * 64 + nj * 16 + r16;
      float bn_ = 0.0f;
      if (BIAS_MODE == 2) bn_ = (col < 512) ? bias[col] : bias2[col - 512];
      #pragma unroll
      for (int r = 0; r < 4; r++) {
        float v = acc[i][nj][r] + ((BIAS_MODE == 1) ? bias[row + r] : bn_);
        C[(long)(row + r) * ldc + col] = (f16)v;
      }
    }
  }
}

// ---------------- r3 256x128 pipelined GEMM (kept for V-proj / PV) ---------
template<int BIAS_MODE>
__global__ __launch_bounds__(512, 2)
void gemm8p(const f16* __restrict__ A, const f16* __restrict__ B,
            f16* __restrict__ C, const float* __restrict__ bias,
            int K, int lda, int ldb, int ldc, long sA, long sB, long sC)
{
  extern __shared__ f16 lds[];
  constexpr int TILE_A = 256 * 64;
  constexpr int TILE_B = 128 * 64;
  constexpr int TILE   = TILE_A + TILE_B;

  const int tid = threadIdx.x, lane = tid & 63, wv = tid >> 6;
  const int bm0 = blockIdx.y * 256, bn0 = blockIdx.x * 128;
  const int wm = (wv >> 1) * 64, wn = (wv & 1) * 64;
  const f16* Ab = A + (long)blockIdx.z * sA + (long)bm0 * lda;
  const f16* Bt = B + (long)blockIdx.z * sB + (long)bn0 * ldb;
  C += (long)blockIdx.z * sC;

  const int r16 = lane & 15, khi = lane >> 4;
  const int sw = (r16 & 7) << 4;

  auto stA = [&](int slot, int k0, int r) {
    int L = (r * 512 + tid) * 16;
    int G = L ^ (((L >> 7) & 7) << 4);
    gload16(Ab + (long)(G >> 7) * lda + k0 + ((G & 127) >> 1),
            lds + (long)slot * TILE + (r * 512 + wv * 64) * 8);
  };
  auto stB = [&](int slot, int k0, int r) {
    int L = (r * 512 + tid) * 16;
    int G = L ^ (((L >> 7) & 7) << 4);
    gload16(Bt + (long)(G >> 7) * ldb + k0 + ((G & 127) >> 1),
            lds + (long)slot * TILE + TILE_A + (r * 512 + wv * 64) * 8);
  };

  f32x4 acc[2][2][4] = {};
  const int nt = K >> 6;

  #pragma unroll
  for (int r = 0; r < 4; r++) stA(0, 0, r);
  #pragma unroll
  for (int r = 0; r < 2; r++) stB(0, 0, r);
  #pragma unroll
  for (int r = 0; r < 4; r++) stA(1, 64, r);
  #pragma unroll
  for (int r = 0; r < 2; r++) stB(1, 64, r);
  asm volatile("s_waitcnt vmcnt(6)" ::: "memory");
  __builtin_amdgcn_s_barrier();

  for (int t = 0; t < nt; t++) {
    const int slot = t % 3;
    const int nslot = (t + 2) % 3;
    const int k2 = (t + 2) << 6;
    const bool st = (t + 2) < nt;
    const char* baseA = (const char*)(lds + (long)slot * TILE);
    const char* baseB = (const char*)(lds + (long)slot * TILE + TILE_A);

    if (st) {
      stA(nslot, k2, 0); stA(nslot, k2, 1); stA(nslot, k2, 2); stA(nslot, k2, 3);
      stB(nslot, k2, 0); stB(nslot, k2, 1);
    }

    f16x8 af0[2], bf0[2], af1[2], bf1[2];
    #pragma unroll
    for (int i = 0; i < 2; i++) {
      af0[i] = *(const f16x8*)(baseA + (((wm + i * 16 + 32 * 0 + r16) * 128 + khi * 16) ^ sw));
      af1[i] = *(const f16x8*)(baseA + (((wm + i * 16 + r16) * 128 + 64 + khi * 16) ^ sw));
      bf0[i] = *(const f16x8*)(baseB + (((wn + i * 16 + r16) * 128 + khi * 16) ^ sw));
      bf1[i] = *(const f16x8*)(baseB + (((wn + i * 16 + r16) * 128 + 64 + khi * 16) ^ sw));
    }
    f16x8 af0b[2], bf0b[2], af1b[2], bf1b[2];
    #pragma unroll
    for (int i = 0; i < 2; i++) {
      af0b[i] = *(const f16x8*)(baseA + (((wm + 32 + i * 16 + r16) * 128 + khi * 16) ^ sw));
      af1b[i] = *(const f16x8*)(baseA + (((wm + 32 + i * 16 + r16) * 128 + 64 + khi * 16) ^ sw));
      bf0b[i] = *(const f16x8*)(baseB + (((wn + 32 + i * 16 + r16) * 128 + khi * 16) ^ sw));
      bf1b[i] = *(const f16x8*)(baseB + (((wn + 32 + i * 16 + r16) * 128 + 64 + khi * 16) ^ sw));
    }

    __builtin_amdgcn_s_setprio(1);
    #pragma unroll
    for (int i = 0; i < 2; i++)
      #pragma unroll
      for (int j = 0; j < 2; j++) {
        acc[i][j][0] = __builtin_amdgcn_mfma_f32_16x16x32_f16(af0[i], bf0[j], acc[i][j][0], 0, 0, 0);
        acc[i][j][0] = __builtin_amdgcn_mfma_f32_16x16x32_f16(af1[i], bf1[j], acc[i][j][0], 0, 0, 0);
        acc[i][j][1] = __builtin_amdgcn_mfma_f32_16x16x32_f16(af0[i], bf0b[j], acc[i][j][1], 0, 0, 0);
        acc[i][j][1] = __builtin_amdgcn_mfma_f32_16x16x32_f16(af1[i], bf1b[j], acc[i][j][1], 0, 0, 0);
        acc[i][j][2] = __builtin_amdgcn_mfma_f32_16x16x32_f16(af0b[i], bf0[j], acc[i][j][2], 0, 0, 0);
        acc[i][j][2] = __builtin_amdgcn_mfma_f32_16x16x32_f16(af1b[i], bf1[j], acc[i][j][2], 0, 0, 0);
        acc[i][j][3] = __builtin_amdgcn_mfma_f32_16x16x32_f16(af0b[i], bf0b[j], acc[i][j][3], 0, 0, 0);
        acc[i][j][3] = __builtin_amdgcn_mfma_f32_16x16x32_f16(af1b[i], bf1b[j], acc[i][j][3], 0, 0, 0);
      }
    __builtin_amdgcn_s_setprio(0);

    __builtin_amdgcn_sched_barrier(0);
    if (st) asm volatile("s_waitcnt vmcnt(6)" ::: "memory");
    else    asm volatile("s_waitcnt vmcnt(0)" ::: "memory");
    __builtin_amdgcn_s_barrier();
  }

  const int rg = khi * 4;
  #pragma unroll
  for (int i = 0; i < 2; i++)
    #pragma unroll
    for (int j = 0; j < 2; j++)
      #pragma unroll
      for (int q = 0; q < 4; q++) {
        const int row = bm0 + wm + (q >> 1) * 32 + i * 16 + rg;
        const int col = bn0 + wn + (q & 1) * 32 + j * 16 + r16;
        const float bn_ = (BIAS_MODE == 2) ? bias[col] : 0.0f;
        #pragma unroll
        for (int r = 0; r < 4; r++) {
          float v = acc[i][j][q][r] + ((BIAS_MODE == 1) ? bias[row + r] : bn_);
          C[(long)(row + r) * ldc + col] = (f16)v;
        }
      }
}

// ---------------- per-row max & sum(exp) of St rows (softmax over q) -------
__global__ __launch_bounds__(256)
void rowstat_kernel(const f16* __restrict__ S, float* __restrict__ maxs,
                    float* __restrict__ sums) {
  __shared__ float red[8];
  const int tid = threadIdx.x;
  const f16* p = S + (long)blockIdx.x * Tt;
  f16x8 v = *((const f16x8*)p + tid);
  float f[8];
  float mx = -3e38f;
  #pragma unroll
  for (int j = 0; j < 8; j++) { f[j] = (float)v[j]; mx = fmaxf(mx, f[j]); }
  #pragma unroll
  for (int off = 1; off < 64; off <<= 1) mx = fmaxf(mx, __shfl_xor(mx, off));
  const int w = tid >> 6;
  if ((tid & 63) == 0) red[w] = mx;
  __syncthreads();
  mx = fmaxf(fmaxf(red[0], red[1]), fmaxf(red[2], red[3]));
  float sum = 0.f;
  #pragma unroll
  for (int j = 0; j < 8; j++) sum += __expf(f[j] - mx);
  #pragma unroll
  for (int off = 1; off < 64; off <<= 1) sum += __shfl_xor(sum, off);
  __syncthreads();
  if ((tid & 63) == 0) red[4 + w] = sum;
  __syncthreads();
  if (tid == 0) {
    maxs[blockIdx.x] = mx;
    sums[blockIdx.x] = (red[4] + red[5]) + (red[6] + red[7]);
  }
}

// ---------------- transpose + normalize: P[b][q][kt] = softmaxed St --------
__global__ __launch_bounds__(256)
void transnorm_kernel(const f16* __restrict__ St, const float* __restrict__ maxs,
                      const float* __restrict__ sums, f16* __restrict__ P) {
  __shared__ f16 tile[64][72];
  __shared__ float rm[64], ri[64];
  const int b = blockIdx.z, kt0 = blockIdx.y * 64, q0 = blockIdx.x * 64;
  const int tid = threadIdx.x;
  if (tid < 64) {
    rm[tid] = maxs[(long)b * Tt + kt0 + tid];
    ri[tid] = 1.0f / sums[(long)b * Tt + kt0 + tid];
  }
  const f16* Sp = St + ((long)b * Tt + kt0) * Tt + q0;
  {
    int r = tid >> 3, c8 = (tid & 7) * 8;
    #pragma unroll
    for (int it = 0; it < 2; it++) {
      f16x8 v = *(const f16x8*)(Sp + (long)(r + it * 32) * Tt + c8);
      *(f16x8*)&tile[r + it * 32][c8] = v;
    }
  }
  __syncthreads();
  f16* Pp = P + ((long)b * Tt + q0) * Tt + kt0;
  {
    int kt8 = (tid & 7) * 8;
    #pragma unroll
    for (int it = 0; it < 2; it++) {
      int q = (tid >> 3) + it * 32;
      f16x8 o;
      #pragma unroll
      for (int jj = 0; jj < 8; jj++) {
        int kt = kt8 + jj;
        o[jj] = (f16)(__expf((float)tile[kt][q] - rm[kt]) * ri[kt]);
      }
      *(f16x8*)(Pp + (long)q * Tt + kt8) = o;
    }
  }
}

// ---------------- BN stats per channel over (b,t) --------------------------
__global__ __launch_bounds__(256)
void bnstat_kernel(const f16* __restrict__ wy, float* __restrict__ bsum,
                   float* __restrict__ bsq) {
  const int c = blockIdx.x, tid = threadIdx.x;
  float s1 = 0.f, s2 = 0.f;
  for (int b = 0; b < Bb; b++) {
    f16x8 v = *((const f16x8*)(wy + ((long)b * Cc + c) * Tt) + tid);
    #pragma unroll
    for (int jj = 0; jj < 8; jj++) { float f = (float)v[jj]; s1 += f; s2 += f * f; }
  }
  #pragma unroll
  for (int off = 1; off < 64; off <<= 1) {
    s1 += __shfl_xor(s1, off);
    s2 += __shfl_xor(s2, off);
  }
  __shared__ float l1[4], l2[4];
  const int w = tid >> 6;
  if ((tid & 63) == 0) { l1[w] = s1; l2[w] = s2; }
  __syncthreads();
  if (tid == 0) {
    bsum[c] = (l1[0] + l1[1]) + (l1[2] + l1[3]);
    bsq[c]  = (l2[0] + l2[1]) + (l2[2] + l2[3]);
  }
}

// ---------------- finalize: BN + residual ----------------------------------
__global__ __launch_bounds__(256)
void final_kernel(const f16* __restrict__ wy, const float* __restrict__ x,
                  const float* __restrict__ gamma, const float* __restrict__ beta,
                  const float* __restrict__ bsum, const float* __restrict__ bsq,
                  float* __restrict__ out)
{
  long i = ((long)blockIdx.x * blockDim.x + threadIdx.x) * 4;
  int c = (int)((i >> 11) & (Cc - 1));
  const float cnt = (float)Bb * (float)Tt;
  float mean = bsum[c] / cnt;
  float var  = bsq[c] / cnt - mean * mean;
  float sc = rsqrtf(var + BN_EPS) * gamma[c];
  float sh = beta[c] - mean * sc;
  f16x4 w = *(const f16x4*)(wy + i);
  float4 xv = *(const float4*)(x + i);
  float4 o;
  o.x = (float)w[0] * sc + sh + xv.x;
  o.y = (float)w[1] * sc + sh + xv.y;
  o.z = (float)w[2] * sc + sh + xv.z;
  o.w = (float)w[3] * sc + sh + xv.w;
  *(float4*)(out + i) = o;
}

// ---------------- host launch ----------------
extern "C" void kernel_launch(void* const* d_in, const int* in_sizes, int n_in,
                              void* d_out, int out_size, void* d_ws, size_t ws_size,
                              hipStream_t stream) {
  const float* x    = (const float*)d_in[0];
  const float* Wq_w = (const float*)d_in[1];
  const float* Wq_b = (const float*)d_in[2];
  const float* Wk_w = (const float*)d_in[3];
  const float* Wk_b = (const float*)d_in[4];
  const float* Wv_w = (const float*)d_in[5];
  const float* Wv_b = (const float*)d_in[6];
  const float* Wo_w = (const float*)d_in[7];
  const float* Wo_b = (const float*)d_in[8];
  const float* gamma = (const float*)d_in[9];
  const float* beta  = (const float*)d_in[10];
  float* out = (float*)d_out;

  constexpr long SZ_XT = (long)Bb * Tt * Cc;   // 16,777,216
  constexpr long SZ_Q  = (long)Bb * Tt * Ci;   // 8,388,608
  constexpr long SZ_S  = (long)Bb * Tt * Tt;   // 33,554,432
  constexpr long SZ_W  = (long)Ci * Cc;        // 524,288

  f16* ws = (f16*)d_ws;
  f16* xT = ws;                 // [B][T][C]   (dead after projections)
  f16* P  = ws;                 // [B][Tq][Tk] overlays xT + QK
  f16* QK = ws + SZ_XT;         // [B][T][1024]: Q = cols 0-511, K = 512-1023
  f16* Vt = QK + 2 * SZ_Q;      // [B][Ci][T]
  f16* St = Vt + SZ_Q;          // [B][Tk][Tq]
  f16* wqk = St + SZ_S;         // [1024][1024] stacked Wq||Wk
  f16* wv = wqk + 2 * SZ_W;
  f16* wo = wv + SZ_W;
  f16* Y  = wo + SZ_W;          // [B][Tq][Ci]
  f16* wy = Y + SZ_Q;           // [B][C][T]
  float* maxs = (float*)(wy + SZ_XT);
  float* sums = maxs + (long)Bb * Tt;
  float* bsum = sums + (long)Bb * Tt;
  float* bsq  = bsum + Cc;

  constexpr int LDSB256 = 2 * 32768 * 2;              // 131072 B
  constexpr int LDSB8P  = (256 * 64 + 128 * 64) * 3 * 2; // 147456 B
  hipFuncSetAttribute(reinterpret_cast<const void*>(gemm256<0>),
                      hipFuncAttributeMaxDynamicSharedMemorySize, LDSB256);
  hipFuncSetAttribute(reinterpret_cast<const void*>(gemm256<1>),
                      hipFuncAttributeMaxDynamicSharedMemorySize, LDSB256);
  hipFuncSetAttribute(reinterpret_cast<const void*>(gemm256<2>),
                      hipFuncAttributeMaxDynamicSharedMemorySize, LDSB256);
  hipFuncSetAttribute(reinterpret_cast<const void*>(gemm8p<0>),
                      hipFuncAttributeMaxDynamicSharedMemorySize, LDSB8P);
  hipFuncSetAttribute(reinterpret_cast<const void*>(gemm8p<1>),
                      hipFuncAttributeMaxDynamicSharedMemorySize, LDSB8P);

  // weight converts (wq||wk stacked)
  cvt_kernel<<<(int)(SZ_W / 4 / 256), 256, 0, stream>>>(Wq_w, wqk, (int)(SZ_W / 4));
  cvt_kernel<<<(int)(SZ_W / 4 / 256), 256, 0, stream>>>(Wk_w, wqk + SZ_W, (int)(SZ_W / 4));
  cvt_kernel<<<(int)(SZ_W / 4 / 256), 256, 0, stream>>>(Wv_w, wv, (int)(SZ_W / 4));
  cvt_kernel<<<(int)(SZ_W / 4 / 256), 256, 0, stream>>>(Wo_w, wo, (int)(SZ_W / 4));
  // x transpose-convert
  cvtT_kernel<<<dim3(Tt / 64, Cc / 64, Bb), 256, 0, stream>>>(x, xT);

  // fused QK projection: QK[t][o] = sum_c xT[t][c] wqk[o][c] + b[o]
  gemm256<2><<<dim3(1024 / 256, Tt / 256, Bb), 512, LDSB256, stream>>>(
      xT, wqk, QK, Wq_b, Wk_b,
      Cc, Cc, Cc, 1024, (long)Tt * Cc, 0, (long)Tt * 1024);

  // Vt[o][t] = sum_c Wv[o][c] xT[t][c] + bv[o]  (bias per m)
  gemm8p<1><<<dim3(Tt / 128, Ci / 256, Bb), 512, LDSB8P, stream>>>(
      wv, xT, Vt, Wv_b, Cc, Cc, Cc, Tt, 0, (long)Tt * Cc, (long)Ci * Tt);

  // St[kt][q] = sum_c K[kt][c] Q[q][c]   (A = QK+512, B = QK, row stride 1024)
  gemm256<0><<<dim3(Tt / 256, Tt / 256, Bb), 512, LDSB256, stream>>>(
      QK + 512, QK, St, nullptr, nullptr,
      Ci, 1024, 1024, Tt, (long)Tt * 1024, (long)Tt * 1024, (long)Tt * Tt);

  // softmax over q: row stats then transpose+normalize into P[q][kt]
  rowstat_kernel<<<Bb * Tt, 256, 0, stream>>>(St, maxs, sums);
  transnorm_kernel<<<dim3(Tt / 64, Tt / 64, Bb), 256, 0, stream>>>(St, maxs, sums, P);

  // Y[q][c] = sum_kt P[q][kt] Vt[c][kt]
  gemm8p<0><<<dim3(Ci / 128, Tt / 256, Bb), 512, LDSB8P, stream>>>(
      P, Vt, Y, nullptr, Tt, Tt, Tt, Ci, (long)Tt * Tt, (long)Ci * Tt, (long)Tt * Ci);

  // wy[o][t] = sum_c Wo[o][c] Y[t][c] + bo[o]  (bias per m)
  gemm256<1><<<dim3(Tt / 256, Cc / 256, Bb), 512, LDSB256, stream>>>(
      wo, Y, wy, Wo_b, nullptr,
      Ci, Ci, Ci, Tt, 0, (long)Tt * Ci, (long)Cc * Tt);

  // BN stats + finalize
  bnstat_kernel<<<Cc, 256, 0, stream>>>(wy, bsum, bsq);
  final_kernel<<<(int)(SZ_XT / 4 / 256), 256, 0, stream>>>(
      wy, x, gamma, beta, bsum, bsq, out);
}